// Round 6
// baseline (223.870 us; speedup 1.0000x reference)
//
#include <hip/hip_runtime.h>

// Problem constants (B=8, H=4096, C=512, GROUPS=4)
constexpr int D         = 128;        // d = C/GROUPS
constexpr int NE        = 512;        // n_embed
constexpr int NROWS     = 131072;     // B*H*GROUPS
constexpr int CC        = 512;        // C
constexpr int OUT_ELEMS = 16777216;   // MROWS*CC

// ws layout (bytes):
//   [0]                 : float diff accumulator
//   [1024, +278528)     : esw - 16 chunks x 17408 B, each chunk:
//        [0,8192)      Eh : fp16(-2E), MFMA A-frag layout
//        [8192,16384)  El : fp16((-2E - Eh)*2048)
//        [16384,17408) en-frag: 3-term bf16 split of ||e||^2 at k=0,1,2
//   [280576, +4194304)  : P[4][512][512] fp32

using half8  = __attribute__((ext_vector_type(8))) _Float16;
using short8 = __attribute__((ext_vector_type(8))) short;
using f32x16 = __attribute__((ext_vector_type(16))) float;

// fp16 min normal: leading term below this is zeroed so the (possibly
// flushed-by-MFMA) denormal carries nothing; residual then holds it all.
#define F16_MINNORM 6.103515625e-05f

static __device__ __forceinline__ unsigned short bf16rn(float x) {
    union { float f; unsigned u; } c; c.f = x;
    unsigned u = c.u;
    return (unsigned short)((u + 0x7FFFu + ((u >> 16) & 1u)) >> 16);
}
static __device__ __forceinline__ float bf16tof(unsigned short h) {
    union { unsigned u; float f; } c; c.u = ((unsigned)h) << 16;
    return c.f;
}

// ---------------------------------------------------------------------------
// Kernel 0: scaled 2-term fp16 split of -2E into MFMA A-frag layout + 3-term
// bf16 split of ||e||^2 into the en-frag; zero the diff accumulator.
// grid = 16 blocks (one per 32-code chunk) x 256 threads.
__global__ void eprep_kernel(const float* __restrict__ embed,
                             unsigned short* __restrict__ esw,
                             float* __restrict__ ws_diff) {
    const int chunk = blockIdx.x;
    const int tid = threadIdx.x;
    const int cl = tid >> 3;    // code in chunk (0..31) == A-row == lane&31
    const int seg = tid & 7;    // k-group of 16 (== kk)
    const float* src = embed + (size_t)(chunk * 32 + cl) * D + seg * 16;
    unsigned short* cb = esw + (size_t)chunk * 8704;  // shorts per chunk

    float ss = 0.f;
#pragma unroll
    for (int g2 = 0; g2 < 2; g2++) {       // g2 == h5 (k-half of the MFMA slice)
        float4 a = ((const float4*)src)[g2 * 2 + 0];
        float4 b = ((const float4*)src)[g2 * 2 + 1];
        float v[8] = {a.x, a.y, a.z, a.w, b.x, b.y, b.z, b.w};
        half8 t1, t2;
#pragma unroll
        for (int i = 0; i < 8; i++) {
            ss += v[i] * v[i];
            float m2 = -2.0f * v[i];
            float m2c = (__builtin_fabsf(m2) < F16_MINNORM) ? 0.0f : m2;
            _Float16 h = (_Float16)m2c;
            float r = m2 - (float)h;
            t1[i] = h;
            t2[i] = (_Float16)(r * 2048.0f);   // scaled residual, fp16-normal
        }
        const int idx = seg * 512 + g2 * 256 + cl * 8;
        *(half8*)(cb + idx) = t1;          // Eh
        *(half8*)(cb + 4096 + idx) = t2;   // El
    }
    // ||e||^2 via 8-lane reduction (threads with same cl are consecutive)
    ss += __shfl_down(ss, 4, 8);
    ss += __shfl_down(ss, 2, 8);
    ss += __shfl_down(ss, 1, 8);
    if (seg == 0) {
        unsigned short e0 = bf16rn(ss);
        float r1 = ss - bf16tof(e0);
        unsigned short e1 = bf16rn(r1);
        unsigned short e2 = bf16rn(r1 - bf16tof(e1));
        short8 en = (short8)0;
        en[0] = (short)e0; en[1] = (short)e1; en[2] = (short)e2;
        *(short8*)(cb + 8192 + cl * 8) = en;             // k=0..7 elems (h5=0)
    }
    if (seg == 1) {
        *(short8*)(cb + 8192 + 256 + cl * 8) = (short8)0; // k=8..15 elems: zero
    }
    if (chunk == 0 && tid == 0) ws_diff[0] = 0.0f;
}

// ---------------------------------------------------------------------------
// Kernel 1: P[g][j][c] = sum_k E[j,k] * W[c, g*128+k]   (fp32, 134 M MAC)
#define AS_STRIDE 68
#define AS_S4 17

__launch_bounds__(256, 4)
__global__ void pgemm_kernel(const float* __restrict__ embed,
                             const float* __restrict__ projw,
                             float* __restrict__ P) {
    __shared__ float As[64 * AS_STRIDE];
    __shared__ float Bs[64 * AS_STRIDE];
    const int tid = threadIdx.x;
    const int cbase = blockIdx.x * 64;   // 8
    const int jbase = blockIdx.y * 64;   // 8
    const int g = blockIdx.z;            // 4
    const int tx = tid & 15, ty = tid >> 4;
    const int r = tid >> 2, seg = tid & 3;

    float acc[4][4];
#pragma unroll
    for (int i = 0; i < 4; i++)
#pragma unroll
        for (int j = 0; j < 4; j++) acc[i][j] = 0.f;

    for (int kb = 0; kb < D; kb += 64) {
        const float4* asrc = (const float4*)(embed + (size_t)(jbase + r) * D + kb + seg * 16);
        const float4* bsrc = (const float4*)(projw + (size_t)(cbase + r) * CC + g * D + kb + seg * 16);
        float4* adst = (float4*)&As[r * AS_STRIDE + seg * 16];
        float4* bdst = (float4*)&Bs[r * AS_STRIDE + seg * 16];
#pragma unroll
        for (int q = 0; q < 4; q++) { adst[q] = asrc[q]; bdst[q] = bsrc[q]; }
        __syncthreads();

        const float4* as4 = (const float4*)As;
        const float4* bs4 = (const float4*)Bs;
#pragma unroll 4
        for (int kk = 0; kk < 16; kk++) {
            float4 a[4], b[4];
#pragma unroll
            for (int i = 0; i < 4; i++) a[i] = as4[(ty + 16 * i) * AS_S4 + kk];
#pragma unroll
            for (int j = 0; j < 4; j++) b[j] = bs4[(tx + 16 * j) * AS_S4 + kk];
#pragma unroll
            for (int i = 0; i < 4; i++)
#pragma unroll
                for (int j = 0; j < 4; j++)
                    acc[i][j] += a[i].x * b[j].x + a[i].y * b[j].y +
                                 a[i].z * b[j].z + a[i].w * b[j].w;
        }
        __syncthreads();
    }
#pragma unroll
    for (int j = 0; j < 4; j++) {
#pragma unroll
        for (int i = 0; i < 4; i++)
            P[(size_t)g * 262144 + (size_t)(jbase + ty + 16 * i) * CC + cbase + tx + 16 * j] =
                acc[i][j];
    }
}

// ---------------------------------------------------------------------------
// Kernel 2: fused MFMA argmin + projection epilogue.
// Wave owns 32 rows. Register budget kept well under the unified VGPR+AGPR
// cap (launch_bounds(256,2) -> 256/wave) so x-frags stay in VGPRs; no spill,
// no accvgpr shuffling. ||e||^2 rides in one bf16 MFMA per chunk (en-frag).
__global__ __launch_bounds__(256, 2)
void argmin_fused_kernel(const float* __restrict__ z,
                         const unsigned short* __restrict__ esw,
                         const float* __restrict__ P,
                         const float* __restrict__ projb,
                         float* __restrict__ ws_diff,
                         float* __restrict__ ind_f,
                         float* __restrict__ out) {
    __shared__ unsigned char ebuf[34816];   // 2 x 17408 B chunk buffers
    __shared__ int ind_s[128];
    const int tid = threadIdx.x;
    const int lane = tid & 63;
    const int wave = __builtin_amdgcn_readfirstlane(tid >> 6);
    const int h5 = lane >> 5, l5 = lane & 31;
    const int rb = blockIdx.x * 128 + wave * 32;

    // X fragments: B-frag for kk holds X[n=l5][k = kk*16 + h5*8 + j]
    half8 x1[8], x2[8];
    float xn = 0.f;
    {
        const float* zr = z + (size_t)(rb + l5) * D + h5 * 8;
#pragma unroll
        for (int kk = 0; kk < 8; kk++) {
            float4 a = *(const float4*)(zr + kk * 16);
            float4 b = *(const float4*)(zr + kk * 16 + 4);
            float v[8] = {a.x, a.y, a.z, a.w, b.x, b.y, b.z, b.w};
            half8 t1, t2;
#pragma unroll
            for (int i = 0; i < 8; i++) {
                xn += v[i] * v[i];
                float vc = (__builtin_fabsf(v[i]) < F16_MINNORM) ? 0.0f : v[i];
                _Float16 h = (_Float16)vc;
                float r = v[i] - (float)h;
                t1[i] = h;
                t2[i] = (_Float16)(r * 2048.0f);
            }
            x1[kk] = t1; x2[kk] = t2;
        }
    }
    // ones frag for the en-term (bf16 1.0 at k=0,1,2; h5=0 lanes only)
    short8 ones = (short8)0;
    if (h5 == 0) { ones[0] = (short)0x3F80; ones[1] = (short)0x3F80; ones[2] = (short)0x3F80; }

    float minv = 3.0e38f;
    int   mini = 0;

    // stage chunk c (17408 B = 17 segs x 1024 B) into buffer b; wave w takes
    // segs w, w+4, ... (wave 0 gets 5). LDS dst = uniform base + lane*16.
    auto stage = [&](int c, int b) {
        const unsigned char* s = (const unsigned char*)esw + (size_t)c * 17408 + lane * 16;
        unsigned char* d = &ebuf[b * 17408] + lane * 16;
        for (int seg = wave; seg < 17; seg += 4)
            __builtin_amdgcn_global_load_lds(
                (const __attribute__((address_space(1))) unsigned int*)(s + seg * 1024),
                (__attribute__((address_space(3))) unsigned int*)(d + seg * 1024),
                16, 0, 0);
    };

    stage(0, 0);
    __syncthreads();

#pragma unroll 1
    for (int c = 0; c < 16; c++) {
        if (c < 15) stage(c + 1, (c + 1) & 1);
        const unsigned char* ldsb = &ebuf[(c & 1) * 17408];

        f32x16 accA, accB;
        {   // en-term: accA[code i][col j] = ||e_i||^2 (exact bf16 3-term)
            short8 aen = *(const short8*)(ldsb + 16384 + h5 * 512 + l5 * 16);
            accA = __builtin_amdgcn_mfma_f32_32x32x16_bf16(aen, ones, (f32x16)(0.0f), 0, 0, 0);
        }
        accB = (f32x16)(0.0f);
#pragma unroll
        for (int kk = 0; kk < 8; kk++) {
            const int fo = kk * 1024 + h5 * 512 + l5 * 16;
            half8 e1 = *(const half8*)(ldsb + fo);
            half8 e2 = *(const half8*)(ldsb + 8192 + fo);
            accA = __builtin_amdgcn_mfma_f32_32x32x16_f16(e1, x1[kk], accA, 0, 0, 0);
            accB = __builtin_amdgcn_mfma_f32_32x32x16_f16(e1, x2[kk], accB, 0, 0, 0);
            accB = __builtin_amdgcn_mfma_f32_32x32x16_f16(e2, x1[kk], accB, 0, 0, 0);
        }

        // scan: dist = accA + 2^-11 * accB ; monotone code order within lane
        const int cb2 = c * 32 + h5 * 4;
#pragma unroll
        for (int r = 0; r < 16; r++) {
            const int cand = cb2 + (r & 3) + 8 * (r >> 2);
            float d0 = fmaf(accB[r], 4.8828125e-4f, accA[r]);
            if (d0 < minv) { minv = d0; mini = cand; }  // strict < keeps first
        }
        __syncthreads();
    }

    // merge the two half-wave code sets for the same x-row (col = lane&31)
    {
        float ov = __shfl_xor(minv, 32);
        int oi = __shfl_xor(mini, 32);
        if (ov < minv || (ov == minv && oi < mini)) { minv = ov; mini = oi; }
    }
    if (lane < 32) {
        ind_f[rb + l5] = (float)mini;
        ind_s[wave * 32 + l5] = mini;
    }

    // diff partial: ||x||^2 (both k-halves) + min proxy, lanes<32 only
    float xfull = xn + __shfl_xor(xn, 32);
    float v = (lane < 32) ? (xfull + minv) : 0.0f;
#pragma unroll
    for (int off = 32; off; off >>= 1) v += __shfl_down(v, off);
    if (lane == 0) atomicAdd(ws_diff, v);

    __syncthreads();   // ind_s ready

    // ---- fused projection epilogue: out[m,c] = sum_g P[g][ind[m,g]][c] + b[c]
    const int mb = blockIdx.x * 32;
    const int c4 = tid & 127;
    const int mh = (tid >> 7) * 16;   // 0 or 16
    const float4 bias = ((const float4*)projb)[c4];
    const float4* P4 = (const float4*)P;
#pragma unroll 4
    for (int u = 0; u < 16; u++) {
        const int ml = mh + u;
        float4 acc = bias;
#pragma unroll
        for (int g = 0; g < 4; g++) {
            const int ig = ind_s[ml * 4 + g];
            float4 p = P4[(size_t)g * 65536 + (size_t)ig * 128 + c4];
            acc.x += p.x; acc.y += p.y; acc.z += p.z; acc.w += p.w;
        }
        ((float4*)out)[(size_t)(mb + ml) * 128 + c4] = acc;
    }
}

// ---------------------------------------------------------------------------
__global__ void finalize_kernel(const float* __restrict__ ws_diff,
                                float* __restrict__ diff_out) {
    // diff = 12.5 * (sum ||x||^2 + sum min(||e||^2 - 2x.e)) / (NROWS*D)
    diff_out[0] = 12.5f * ws_diff[0] * (1.0f / 16777216.0f);
}

// ---------------------------------------------------------------------------
extern "C" void kernel_launch(void* const* d_in, const int* in_sizes, int n_in,
                              void* d_out, int out_size, void* d_ws, size_t ws_size,
                              hipStream_t stream) {
    const float* z     = (const float*)d_in[0];
    const float* embed = (const float*)d_in[1];
    const float* projw = (const float*)d_in[2];
    const float* projb = (const float*)d_in[3];

    float* out      = (float*)d_out;
    float* diff_out = out + OUT_ELEMS;
    float* ind_f    = out + OUT_ELEMS + 1;

    char* wsb = (char*)d_ws;
    float* ws_diff = (float*)wsb;
    unsigned short* esw = (unsigned short*)(wsb + 1024);
    float* P = (float*)(wsb + 280576);

    eprep_kernel<<<16, 256, 0, stream>>>(embed, esw, ws_diff);
    pgemm_kernel<<<dim3(8, 8, 4), 256, 0, stream>>>(embed, projw, P);
    argmin_fused_kernel<<<NROWS / 128, 256, 0, stream>>>(z, esw, P, projb,
                                                         ws_diff, ind_f, out);
    finalize_kernel<<<1, 1, 0, stream>>>(ws_diff, diff_out);
}